// Round 1
// baseline (214.390 us; speedup 1.0000x reference)
//
#include <hip/hip_runtime.h>

// CrossScaleAttention: out = softmax(l2n(Q) l2n(K)^T * 32^-0.5) V
// B=4, Nq=Nk=4096, D=256, fp32 in/out.
// Scores bounded by +-0.1768 => no online max needed: O += exp(S)V, l += rowsum, divide at end.

#define NQ 4096
#define NK 4096
#define DIM 256
#define NROWS 16384      // B*NQ
#define BM 128           // q rows per workgroup
#define BN 64            // keys per iteration
#define KSPLIT 2
#define NITER 32         // (NK/KSPLIT)/BN

typedef __attribute__((ext_vector_type(8))) short bf16x8;
typedef __attribute__((ext_vector_type(4))) float f32x4;
typedef __attribute__((ext_vector_type(16))) float f32x16;

__device__ __forceinline__ unsigned short f2bf(float f) {
  unsigned int u = __float_as_uint(f);
  u += 0x7fffu + ((u >> 16) & 1u);            // RNE
  return (unsigned short)(u >> 16);
}

__device__ __forceinline__ void gload16(const void* g, void* l) {
  __builtin_amdgcn_global_load_lds(
      (const __attribute__((address_space(1))) unsigned int*)g,
      (__attribute__((address_space(3))) unsigned int*)l, 16, 0, 0);
}

// ---------------------------------------------------------------------------
// prep_qk: L2-normalize Q and K rows.
//  Q -> A-fragment-major bf16 (16x16x32 MFMA A layout), scale folded: *SCALE*log2(e)
//  K -> tile-chunk-major bf16: [row_tile64][d_chunk32][row64][8 elts] for LDS staging
// One wave per 256-elt row; 4 rows per 256-thr block; rows 0..16383=Q, 16384..=K.
// ---------------------------------------------------------------------------
__global__ __launch_bounds__(256) void prep_qk(
    const float* __restrict__ Q, const float* __restrict__ K,
    unsigned short* __restrict__ Qfm, unsigned short* __restrict__ Kfm)
{
  const int wave = threadIdx.x >> 6, lane = threadIdx.x & 63;
  const int r = blockIdx.x * 4 + wave;
  const bool isQ = r < NROWS;
  const int R = isQ ? r : r - NROWS;
  const float* src = (isQ ? Q : K) + (size_t)R * DIM + lane * 4;
  float4 v = *(const float4*)src;
  float ss = v.x*v.x + v.y*v.y + v.z*v.z + v.w*v.w;
  #pragma unroll
  for (int off = 1; off < 64; off <<= 1) ss += __shfl_xor(ss, off, 64);
  float scale = 1.0f / fmaxf(sqrtf(ss), 1e-12f);
  if (isQ) scale *= (0.17677669529663687f * 1.4426950408889634f); // SCALE*log2e
  unsigned short b0 = f2bf(v.x*scale), b1 = f2bf(v.y*scale),
                 b2 = f2bf(v.z*scale), b3 = f2bf(v.w*scale);
  ushort4 o; o.x = b0; o.y = b1; o.z = b2; o.w = b3;
  if (isQ) {
    // element (R,d): mb=R>>4, fraglane=(R&15)+16*((d>>3)&3), kg=d>>5, j=d&7
    const int mb = R >> 4, m = R & 15;
    const int kg = lane >> 3, fl = m + 16 * ((lane >> 1) & 3), j0 = 4 * (lane & 1);
    *(ushort4*)(Qfm + ((size_t)(mb*8 + kg)*64 + fl)*8 + j0) = o;
  } else {
    // element (R,d): tile=R>>6, c=d>>3, n=R&63, j=d&7
    const int kt = R >> 6, n = R & 63;
    const int c = lane >> 1, j0 = 4 * (lane & 1);
    *(ushort4*)(Kfm + ((size_t)(kt*32 + c)*64 + n)*8 + j0) = o;
  }
}

// ---------------------------------------------------------------------------
// prep_v: V -> B-fragment-major bf16 for 32x32x16 MFMA:
// slot[(NS*8+db)*64+lane][j] holds V[n=NS*16+(lane>>5)*8+j][d=db*32+(lane&31)]
// One block per 16-row n-tile (NS global, 1024 blocks).
// ---------------------------------------------------------------------------
__global__ __launch_bounds__(256) void prep_v(
    const float* __restrict__ V, unsigned short* __restrict__ Vfm)
{
  const int NS = blockIdx.x;
  const int t = threadIdx.x;
  #pragma unroll
  for (int i = 0; i < 4; i++) {
    const int e = t + 256*i;          // 0..1023
    const int nl = e >> 6;            // 0..15 row in tile
    const int d  = (e & 63) * 4;      // 0..252
    float4 v = *(const float4*)(V + ((size_t)NS*16 + nl)*DIM + d);
    const int db = d >> 5;
    const int lane = (d & 31) + 32*((nl >> 3) & 1);
    const int j = nl & 7;
    size_t base = ((size_t)(NS*8 + db)*64 + lane)*8 + j;
    Vfm[base]      = f2bf(v.x);
    Vfm[base + 8]  = f2bf(v.y);
    Vfm[base + 16] = f2bf(v.z);
    Vfm[base + 24] = f2bf(v.w);
  }
}

// ---------------------------------------------------------------------------
// Main attention kernel. grid=256: block -> (b, ks, qt) with (b,ks) = blk&7 so
// each XCD's resident blocks share one K/V half (L2 locality). 512 thr = 8 waves.
// S-phase: 16x16x32 MFMA, wave (mi=w>>1, ni=w&1) computes 32m x 32n (2x2 tiles).
// O-phase: 32x32x16 MFMA, wave (mi2=w>>2, dh=w&3) computes 64m x 64d (2x2 tiles).
// K tile staged to LDS via global_load_lds, prefetched during O-phase.
// P (exp scores) via XOR-swizzled LDS (conflict-free b128 A-frag reads).
// ---------------------------------------------------------------------------
__global__ __launch_bounds__(512, 2) void attn(
    const unsigned short* __restrict__ Qfm,
    const unsigned short* __restrict__ Kfm,
    const unsigned short* __restrict__ Vfm,
    float* __restrict__ Opart, float* __restrict__ lpart)
{
  __shared__ unsigned short Klds[64 * 256];   // 32 KB, chunk layout [c:32][n:64][8]
  __shared__ unsigned short Plds[128 * 64];   // 16 KB, row-major, chunk XOR-swizzle

  const int tid = threadIdx.x, wave = tid >> 6, lane = tid & 63;
  const int blk = blockIdx.x;
  const int g = blk & 7, qt = blk >> 3;
  const int b = g >> 1, ks = g & 1;
  const int Rq0 = b*NQ + qt*BM;               // global q-row base
  const int MB0 = Rq0 >> 4;
  const int n0base = b*NQ + ks*(NK/KSPLIT);   // global key-row base
  const int mi = wave >> 1, ni = wave & 1;    // S-phase role
  const int mi2 = wave >> 2, dh = wave & 3;   // O-phase role

  // Q A-frags (persist in registers, 64 VGPRs)
  bf16x8 qf[2][8];
  #pragma unroll
  for (int mt = 0; mt < 2; mt++) {
    const int mb = MB0 + mi*2 + mt;
    #pragma unroll
    for (int kg = 0; kg < 8; kg++)
      qf[mt][kg] = *(const bf16x8*)(Qfm + ((size_t)(mb*8 + kg)*64 + lane)*8);
  }

  f32x16 oacc[2][2] = {};
  float lacc[2][4] = {};

  // stage K tile kt into Klds: wave w stages d-chunks c=4w..4w+3, lane = key row
  auto stage = [&](int kt) {
    const int ktile = (n0base + kt*BN) >> 6;
    #pragma unroll
    for (int jj = 0; jj < 4; jj++) {
      const int c = wave*4 + jj;
      gload16(Kfm + ((size_t)(ktile*32 + c)*64 + lane)*8, Klds + (size_t)c*512);
    }
  };

  stage(0);

  for (int kt = 0; kt < NITER; kt++) {
    __syncthreads();   // K tile ready; previous P fully consumed

    // ---- S = Qhat Khat^T (already * SCALE*log2e) ----
    f32x4 sacc[2][2] = {};
    #pragma unroll
    for (int kg = 0; kg < 8; kg++) {
      bf16x8 kf[2];
      #pragma unroll
      for (int nt = 0; nt < 2; nt++) {
        const int nrow = ni*32 + nt*16 + (lane & 15);
        const int c = kg*4 + (lane >> 4);
        kf[nt] = *(const bf16x8*)(Klds + ((size_t)(c*64 + nrow))*8);
      }
      #pragma unroll
      for (int mt = 0; mt < 2; mt++)
        #pragma unroll
        for (int nt = 0; nt < 2; nt++)
          sacc[mt][nt] = __builtin_amdgcn_mfma_f32_16x16x32_bf16(
              qf[mt][kg], kf[nt], sacc[mt][nt], 0, 0, 0);
    }

    // ---- P = exp2(S); accumulate row-sums; write P to swizzled LDS ----
    #pragma unroll
    for (int mt = 0; mt < 2; mt++)
      #pragma unroll
      for (int nt = 0; nt < 2; nt++)
        #pragma unroll
        for (int r = 0; r < 4; r++) {
          float p = __builtin_amdgcn_exp2f(sacc[mt][nt][r]);
          lacc[mt][r] += p;
          const int m = mi*32 + mt*16 + 4*(lane >> 4) + r;
          const int n = ni*32 + nt*16 + (lane & 15);
          const int cc = (n >> 3) ^ (m & 7);
          Plds[m*64 + cc*8 + (n & 7)] = f2bf(p);
        }

    __syncthreads();   // P visible; all K reads done -> K buffer free

    if (kt + 1 < NITER) stage(kt + 1);   // prefetch next K during O-phase

    // ---- O += P V ----
    const int NB0 = (n0base + kt*BN) >> 4;
    #pragma unroll
    for (int kstep = 0; kstep < 4; kstep++) {
      bf16x8 pf[2], vf[2];
      #pragma unroll
      for (int mt2 = 0; mt2 < 2; mt2++) {
        const int m = mi2*64 + mt2*32 + (lane & 31);
        const int c2 = kstep*2 + (lane >> 5);
        pf[mt2] = *(const bf16x8*)(Plds + m*64 + ((c2 ^ (m & 7)) * 8));
      }
      #pragma unroll
      for (int dt = 0; dt < 2; dt++) {
        const int db = dh*2 + dt;
        vf[dt] = *(const bf16x8*)(Vfm + ((size_t)((NB0 + kstep)*8 + db)*64 + lane)*8);
      }
      #pragma unroll
      for (int mt2 = 0; mt2 < 2; mt2++)
        #pragma unroll
        for (int dt = 0; dt < 2; dt++)
          oacc[mt2][dt] = __builtin_amdgcn_mfma_f32_32x32x16_bf16(
              pf[mt2], vf[dt], oacc[mt2][dt], 0, 0, 0);
    }
  }

  // ---- epilogue: row-sums (butterfly over the 16-lane col group) + stores ----
  #pragma unroll
  for (int mt = 0; mt < 2; mt++)
    #pragma unroll
    for (int r = 0; r < 4; r++) {
      float s = lacc[mt][r];
      s += __shfl_xor(s, 1, 64); s += __shfl_xor(s, 2, 64);
      s += __shfl_xor(s, 4, 64); s += __shfl_xor(s, 8, 64);
      if ((lane & 15) == 0) {
        const int m = mi*32 + mt*16 + 4*(lane >> 4) + r;
        lpart[(size_t)(ks*2 + ni)*NROWS + Rq0 + m] = s;
      }
    }

  #pragma unroll
  for (int mt2 = 0; mt2 < 2; mt2++)
    #pragma unroll
    for (int dt = 0; dt < 2; dt++)
      #pragma unroll
      for (int reg = 0; reg < 16; reg++) {
        const int m = mi2*64 + mt2*32 + 4*(lane >> 5) + (reg & 3) + 8*(reg >> 2);
        const int d = dh*64 + dt*32 + (lane & 31);
        Opart[((size_t)(ks*NROWS + Rq0 + m))*DIM + d] = oacc[mt2][dt][reg];
      }
}

// ---------------------------------------------------------------------------
// combine: out = (O0+O1) / (l00+l01+l10+l11)
// ---------------------------------------------------------------------------
__global__ __launch_bounds__(256) void combine(
    const float* __restrict__ Opart, const float* __restrict__ lpart,
    float* __restrict__ out)
{
  const size_t idx = (size_t)blockIdx.x*256 + threadIdx.x;
  const size_t e = idx*4;
  const int R = (int)(e >> 8);
  float4 a = *(const float4*)(Opart + e);
  float4 c = *(const float4*)(Opart + (size_t)NROWS*DIM + e);
  float ls = lpart[R] + lpart[NROWS + R] + lpart[2*NROWS + R] + lpart[3*NROWS + R];
  float inv = 1.0f / ls;
  float4 o;
  o.x = (a.x + c.x)*inv; o.y = (a.y + c.y)*inv;
  o.z = (a.z + c.z)*inv; o.w = (a.w + c.w)*inv;
  *(float4*)(out + e) = o;
}

extern "C" void kernel_launch(void* const* d_in, const int* in_sizes, int n_in,
                              void* d_out, int out_size, void* d_ws, size_t ws_size,
                              hipStream_t stream) {
  const float* Q = (const float*)d_in[0];
  const float* K = (const float*)d_in[1];
  const float* V = (const float*)d_in[2];
  char* ws = (char*)d_ws;
  // workspace layout (bytes): Qfm 8 MiB | Kfm 8 MiB | Vfm 8 MiB | Opart 32 MiB | lpart 256 KiB
  unsigned short* Qfm = (unsigned short*)(ws);
  unsigned short* Kfm = (unsigned short*)(ws + 8388608);
  unsigned short* Vfm = (unsigned short*)(ws + 16777216);
  float* Opart = (float*)(ws + 25165824);
  float* lpart = (float*)(ws + 58720256);

  prep_qk<<<8192, 256, 0, stream>>>(Q, K, Qfm, Kfm);
  prep_v<<<1024, 256, 0, stream>>>(V, Vfm);
  attn<<<256, 512, 0, stream>>>(Qfm, Kfm, Vfm, Opart, lpart);
  combine<<<4096, 256, 0, stream>>>(Opart, lpart, (float*)d_out);
}

// Round 3
// 180.904 us; speedup vs baseline: 1.1851x; 1.1851x over previous
//
#include <hip/hip_runtime.h>

// CrossScaleAttention: out = softmax(l2n(Q) l2n(K)^T * 32^-0.5) V
// B=4, Nq=Nk=4096, D=256, fp32 in/out.
// |scores| <= 0.1768 => no online max: O += exp(S) V, l += rowsum, divide at end.
// R2: S^T trick (swap MFMA operands) -> packed b64 P-writes; 2 blocks/CU; merged prep.
// R3: fix typo qf[mt] -> qf[mt][kg] in S-phase MFMA.

#define NQ 4096
#define DIM 256
#define NROWS 16384      // B*NQ
#define BM 64            // q rows per workgroup
#define BN 64            // keys per iteration
#define KSPLIT 2
#define NITER 32         // (4096/KSPLIT)/BN
#define PSTRIDE 68       // Plds row stride (ushorts): 64 + 4 pad for bank spread

typedef __attribute__((ext_vector_type(8))) short bf16x8;
typedef __attribute__((ext_vector_type(4))) float f32x4;
typedef __attribute__((ext_vector_type(16))) float f32x16;

__device__ __forceinline__ unsigned short f2bf(float f) {
  unsigned int u = __float_as_uint(f);
  u += 0x7fffu + ((u >> 16) & 1u);            // RNE
  return (unsigned short)(u >> 16);
}

// pack two positive floats to bf16 pair (round half up; ties-only deviation from RNE)
__device__ __forceinline__ unsigned int pack2bf(float a, float b) {
  unsigned int ua = __float_as_uint(a) + 0x8000u;
  unsigned int ub = __float_as_uint(b) + 0x8000u;
  return __builtin_amdgcn_perm(ub, ua, 0x07060302u);  // [ua.hi16 | ub.hi16]
}

__device__ __forceinline__ void gload16(const void* g, void* l) {
  __builtin_amdgcn_global_load_lds(
      (const __attribute__((address_space(1))) unsigned int*)g,
      (__attribute__((address_space(3))) unsigned int*)l, 16, 0, 0);
}

// ---------------------------------------------------------------------------
// prep (merged): blocks [0,8192): Q/K row normalize. blocks [8192,9216): V transpose.
//  Q -> row-major bf16, scale folded (*SCALE*log2e). Coalesced 512B/row writes.
//  K -> chunk-major bf16 [row_tile64][d_chunk32][row64][8] for global_load_lds staging.
//  V -> B-frag-major bf16 via LDS transpose; 16B coalesced global writes.
// ---------------------------------------------------------------------------
__global__ __launch_bounds__(256) void prep(
    const float* __restrict__ Q, const float* __restrict__ K,
    const float* __restrict__ V,
    unsigned short* __restrict__ Qrm, unsigned short* __restrict__ Kfm,
    unsigned short* __restrict__ Vfm)
{
  __shared__ unsigned short vt[16 * 264];
  const int blk = blockIdx.x, tid = threadIdx.x;
  if (blk < 8192) {
    const int wave = tid >> 6, lane = tid & 63;
    const int r = blk * 4 + wave;
    const bool isQ = r < NROWS;
    const int R = isQ ? r : r - NROWS;
    float4 v = *(const float4*)((isQ ? Q : K) + (size_t)R * DIM + lane * 4);
    float ss = v.x*v.x + v.y*v.y + v.z*v.z + v.w*v.w;
    #pragma unroll
    for (int off = 1; off < 64; off <<= 1) ss += __shfl_xor(ss, off, 64);
    float scale = 1.0f / fmaxf(sqrtf(ss), 1e-12f);
    if (isQ) scale *= (0.17677669529663687f * 1.4426950408889634f); // SCALE*log2e
    ushort4 o;
    o.x = f2bf(v.x*scale); o.y = f2bf(v.y*scale);
    o.z = f2bf(v.z*scale); o.w = f2bf(v.w*scale);
    if (isQ) {
      *(ushort4*)(Qrm + (size_t)R * DIM + lane * 4) = o;      // coalesced
    } else {
      const int kt = R >> 6, n = R & 63;
      const int c = lane >> 1, j0 = 4 * (lane & 1);
      *(ushort4*)(Kfm + ((size_t)(kt*32 + c)*64 + n)*8 + j0) = o;
    }
  } else {
    // V tile NS: 16 rows. Read coalesced -> LDS; transpose-gather -> 16B coalesced write.
    const int NS = blk - 8192;
    #pragma unroll
    for (int i = 0; i < 4; i++) {
      const int e = tid + 256*i;
      const int nl = e >> 6, d = (e & 63) * 4;
      float4 v = *(const float4*)(V + ((size_t)NS*16 + nl)*DIM + d);
      ushort4 o;
      o.x = f2bf(v.x); o.y = f2bf(v.y); o.z = f2bf(v.z); o.w = f2bf(v.w);
      *(ushort4*)(vt + nl*264 + d) = o;
    }
    __syncthreads();
    #pragma unroll
    for (int i = 0; i < 2; i++) {
      const int ch = tid + 256*i;            // 0..511 chunks of 16B
      const int db = ch >> 6, ln = ch & 63;
      const int row0 = (ln >> 5) * 8, dd = db*32 + (ln & 31);
      ushort4 a, b;
      a.x = vt[(row0+0)*264 + dd]; a.y = vt[(row0+1)*264 + dd];
      a.z = vt[(row0+2)*264 + dd]; a.w = vt[(row0+3)*264 + dd];
      b.x = vt[(row0+4)*264 + dd]; b.y = vt[(row0+5)*264 + dd];
      b.z = vt[(row0+6)*264 + dd]; b.w = vt[(row0+7)*264 + dd];
      size_t base = ((size_t)(NS*8 + db)*64 + ln)*8;
      *(ushort4*)(Vfm + base)     = a;
      *(ushort4*)(Vfm + base + 4) = b;
    }
  }
}

// ---------------------------------------------------------------------------
// Main attention kernel. grid=512, 256 thr (4 waves), 2 blocks/CU.
// blk&7 -> (b,ks) so same-XCD blocks share one K/V half (fits 4 MiB L2).
// S^T-phase: sacc = mfma16x16x32(A=kf, B=qf) -> C col = q-row, rows = 4 consec keys.
//   Wave (mi=w&1, ni=w>>1): 32n x 32m. P packed to Plds[m][n] via 2x b64/tile.
// O-phase: 32x32x16, wave w owns d-range 64 (dt 2 tiles), m full 64 (mt2 2 tiles).
// K staged via global_load_lds (prefetched during O-phase); V frag-major from L2.
// ---------------------------------------------------------------------------
__global__ __launch_bounds__(256, 2) void attn(
    const unsigned short* __restrict__ Qrm,
    const unsigned short* __restrict__ Kfm,
    const unsigned short* __restrict__ Vfm,
    float* __restrict__ Opart, float* __restrict__ lpart)
{
  __shared__ unsigned short Klds[32 * 64 * 8];     // 32 KB chunk layout [c:32][n:64][8]
  __shared__ unsigned short Plds[BM * PSTRIDE];    // 8704 B row-major padded

  const int tid = threadIdx.x, wave = tid >> 6, lane = tid & 63;
  const int l15 = lane & 15, l4 = lane >> 4;
  const int blk = blockIdx.x;
  const int g = blk & 7, qt = blk >> 3;
  const int b = g >> 1, ks = g & 1;
  const int Rq0 = b*NQ + qt*BM;
  const int n0base = b*NQ + ks*(NQ/KSPLIT);
  const int mi = wave & 1, ni = wave >> 1;

  // Q B-frags from row-major: qf[mt][kg], m = mi*32+mt*16+l15, k = kg*32+l4*8
  bf16x8 qf[2][8];
  #pragma unroll
  for (int mt = 0; mt < 2; mt++) {
    const unsigned short* qrow = Qrm + (size_t)(Rq0 + mi*32 + mt*16 + l15) * DIM + l4*8;
    #pragma unroll
    for (int kg = 0; kg < 8; kg++)
      qf[mt][kg] = *(const bf16x8*)(qrow + kg*32);
  }

  f32x16 oacc[2][2] = {};   // [mt2][dt]
  float lacc[2] = {};       // [mt], per-lane partial over (ni strip, q-group)

  auto stage = [&](int kt) {
    const unsigned short* src = Kfm + (size_t)((n0base + kt*BN) >> 6) * (32*64*8);
    #pragma unroll
    for (int jj = 0; jj < 4; jj++) {
      const int c = wave*8 + jj*2;      // 2 chunks per step, 8 total per wave
      gload16(src + (size_t)c*512 + lane*8,       Klds + (size_t)c*512);
      gload16(src + (size_t)(c+1)*512 + lane*8,   Klds + (size_t)(c+1)*512);
    }
  };

  stage(0);

  for (int kt = 0; kt < NITER; kt++) {
    __syncthreads();   // K tile ready; previous P fully consumed

    // ---- S^T = Khat Qhat^T (scale folded into Q) ----
    f32x4 sacc[2][2] = {};   // [nt][mt]
    #pragma unroll
    for (int kg = 0; kg < 8; kg++) {
      bf16x8 kf[2];
      #pragma unroll
      for (int nt = 0; nt < 2; nt++) {
        const int nrow = ni*32 + nt*16 + l15;
        const int c = kg*4 + l4;
        kf[nt] = *(const bf16x8*)(Klds + ((size_t)(c*64 + nrow))*8);
      }
      #pragma unroll
      for (int nt = 0; nt < 2; nt++)
        #pragma unroll
        for (int mt = 0; mt < 2; mt++)
          sacc[nt][mt] = __builtin_amdgcn_mfma_f32_16x16x32_bf16(
              kf[nt], qf[mt][kg], sacc[nt][mt], 0, 0, 0);
    }

    // ---- P = exp2(S); row-sums; packed b64 writes to Plds[m][n] ----
    #pragma unroll
    for (int nt = 0; nt < 2; nt++)
      #pragma unroll
      for (int mt = 0; mt < 2; mt++) {
        float p0 = __builtin_amdgcn_exp2f(sacc[nt][mt][0]);
        float p1 = __builtin_amdgcn_exp2f(sacc[nt][mt][1]);
        float p2 = __builtin_amdgcn_exp2f(sacc[nt][mt][2]);
        float p3 = __builtin_amdgcn_exp2f(sacc[nt][mt][3]);
        lacc[mt] += (p0 + p1) + (p2 + p3);
        uint2 pk;
        pk.x = pack2bf(p0, p1);
        pk.y = pack2bf(p2, p3);
        const int m = mi*32 + mt*16 + l15;
        const int n = ni*32 + nt*16 + 4*l4;
        *(uint2*)(Plds + m*PSTRIDE + n) = pk;
      }

    __syncthreads();   // P visible; K reads done -> K buffer free

    if (kt + 1 < NITER) stage(kt + 1);   // prefetch next K during O-phase

    // ---- O += P V ----
    const int NB0 = (n0base + kt*BN) >> 4;
    #pragma unroll
    for (int kstep = 0; kstep < 4; kstep++) {
      bf16x8 pf[2], vf[2];
      #pragma unroll
      for (int mt2 = 0; mt2 < 2; mt2++)
        pf[mt2] = *(const bf16x8*)(Plds + (mt2*32 + (lane & 31))*PSTRIDE
                                   + kstep*16 + 8*(lane >> 5));
      #pragma unroll
      for (int dt = 0; dt < 2; dt++) {
        const int db = wave*2 + dt;
        vf[dt] = *(const bf16x8*)(Vfm + ((size_t)((NB0 + kstep)*8 + db)*64 + lane)*8);
      }
      #pragma unroll
      for (int mt2 = 0; mt2 < 2; mt2++)
        #pragma unroll
        for (int dt = 0; dt < 2; dt++)
          oacc[mt2][dt] = __builtin_amdgcn_mfma_f32_32x32x16_bf16(
              pf[mt2], vf[dt], oacc[mt2][dt], 0, 0, 0);
    }
  }

  // ---- epilogue: l row-sums (reduce over q-groups) ----
  #pragma unroll
  for (int mt = 0; mt < 2; mt++) {
    float s = lacc[mt];
    s += __shfl_xor(s, 16, 64);
    s += __shfl_xor(s, 32, 64);
    if (l4 == 0)
      lpart[(size_t)(ks*2 + ni)*NROWS + Rq0 + mi*32 + mt*16 + l15] = s;
  }

  // ---- epilogue: O stores (coalesced 128B per 32-lane group) ----
  #pragma unroll
  for (int mt2 = 0; mt2 < 2; mt2++)
    #pragma unroll
    for (int dt = 0; dt < 2; dt++)
      #pragma unroll
      for (int reg = 0; reg < 16; reg++) {
        const int m = mt2*32 + 4*(lane >> 5) + (reg & 3) + 8*(reg >> 2);
        const int d = wave*64 + dt*32 + (lane & 31);
        Opart[((size_t)(ks*NROWS + Rq0 + m))*DIM + d] = oacc[mt2][dt][reg];
      }
}

// ---------------------------------------------------------------------------
// combine: out = (O0+O1) / (l00+l01+l10+l11)
// ---------------------------------------------------------------------------
__global__ __launch_bounds__(256) void combine(
    const float* __restrict__ Opart, const float* __restrict__ lpart,
    float* __restrict__ out)
{
  const size_t idx = (size_t)blockIdx.x*256 + threadIdx.x;
  const size_t e = idx*4;
  const int R = (int)(e >> 8);
  float4 a = *(const float4*)(Opart + e);
  float4 c = *(const float4*)(Opart + (size_t)NROWS*DIM + e);
  float ls = lpart[R] + lpart[NROWS + R] + lpart[2*NROWS + R] + lpart[3*NROWS + R];
  float inv = 1.0f / ls;
  float4 o;
  o.x = (a.x + c.x)*inv; o.y = (a.y + c.y)*inv;
  o.z = (a.z + c.z)*inv; o.w = (a.w + c.w)*inv;
  *(float4*)(out + e) = o;
}

extern "C" void kernel_launch(void* const* d_in, const int* in_sizes, int n_in,
                              void* d_out, int out_size, void* d_ws, size_t ws_size,
                              hipStream_t stream) {
  const float* Q = (const float*)d_in[0];
  const float* K = (const float*)d_in[1];
  const float* V = (const float*)d_in[2];
  char* ws = (char*)d_ws;
  // ws layout: Qrm 8 MiB | Kfm 8 MiB | Vfm 8 MiB | Opart 32 MiB | lpart 256 KiB
  unsigned short* Qrm = (unsigned short*)(ws);
  unsigned short* Kfm = (unsigned short*)(ws + 8388608);
  unsigned short* Vfm = (unsigned short*)(ws + 16777216);
  float* Opart = (float*)(ws + 25165824);
  float* lpart = (float*)(ws + 58720256);

  prep<<<9216, 256, 0, stream>>>(Q, K, V, Qrm, Kfm, Vfm);
  attn<<<512, 256, 0, stream>>>(Qrm, Kfm, Vfm, Opart, lpart);
  combine<<<4096, 256, 0, stream>>>(Opart, lpart, (float*)d_out);
}